// Round 4
// baseline (321.256 us; speedup 1.0000x reference)
//
#include <hip/hip_runtime.h>

// ARIMA flow sampling, R4: transposed MFMA + 2x2 wave split.
// B=1024,Q=96,C=16,H=100, 100 Euler steps; 16384 rows = (b,c).
// Grid 512 WGs x 256 thr (4 waves). WG owns 32 rows. Wave (rw,nw):
//   rw = row-group (16 rows), nw = neuron-group.
// Transposed GEMM: A = weights (VGPRs, loaded once), B = activations
// (LDS bf16 [row][feat], STR=136). D: col=lane&15 -> row, reg -> feat
// => lane's 4 regs contiguous feats -> single ds_write_b64.
// R3->R4: neuron split 4->2 groups halves LDS B-read amplification (the
// shared-LDS-pipe bottleneck); asymmetric tiles (4,3,4)/(3,4,3) keep max
// weight VGPRs at 176 (duplicated code paths so live ranges don't sum).
// tanh = Pade(5,4)+clamp: one rcp, no exp (transcendentals are 1/4 rate).
// Bias/t folded as input feats: x: 97=t, 98=1.0 ; h: 100=1.0. Zero acc init.
// x master + noise(=x0) stay fp32 in owner-lane registers.

#define NB 1024
#define NQ 96
#define NC 16
#define NH 100
#define QP1 97
#define QP2 98
#define ROWS 32
#define NTHR 256
#define STR 136
#define NSTEPS_ 100

typedef __attribute__((ext_vector_type(8))) short bf16x8;
typedef __attribute__((ext_vector_type(4))) float f32x4;
typedef __attribute__((ext_vector_type(2))) unsigned uintx2;

__device__ __forceinline__ short f2bf_rne(float f) {  // one-time loads only
  unsigned u = __builtin_bit_cast(unsigned, f);
  u = u + 0x7fffu + ((u >> 16) & 1u);
  return (short)(u >> 16);
}

__device__ __forceinline__ unsigned bfhi(float f) {  // half-up bf16 bits
  return (__builtin_bit_cast(unsigned, f) + 0x8000u) >> 16;
}

// pack two half-up bf16 into one dword: lo=bf(a), hi=bf(b)
__device__ __forceinline__ unsigned pack_bf2(float a, float b) {
  unsigned ua = __builtin_bit_cast(unsigned, a) + 0x8000u;
  unsigned ub = __builtin_bit_cast(unsigned, b) + 0x8000u;
  return __builtin_amdgcn_perm(ub, ua, 0x07060302);
}

// Pade(5,4) tanh + clamp: err <= ~7e-4 over all x (saturates via clamp).
__device__ __forceinline__ float fast_tanh(float x) {
  float u = x * x;
  float num = x * fmaf(u + 105.0f, u, 945.0f);
  float den = fmaf(fmaf(15.0f, u, 420.0f), u, 945.0f);
  float v = num * __builtin_amdgcn_rcpf(den);
  return fminf(fmaxf(v, -1.0f), 1.0f);
}

// Weight A-frag: lane holds W'[m][k], m = g*16 + col, k = kb*32+quad*8+j.
// k<KW -> W[m][k]; k==KW -> bias[m]; else 0. m>=mvalid -> 0.
__device__ void load_afrag(const float* __restrict__ W,
                           const float* __restrict__ bias, int ws, int mvalid,
                           int KW, int m, int quad, bf16x8 dst[4]) {
#pragma unroll
  for (int kb = 0; kb < 4; ++kb) {
    bf16x8 v;
#pragma unroll
    for (int i = 0; i < 8; ++i) {
      int k = kb * 32 + quad * 8 + i;
      float f = 0.0f;
      if (m < mvalid) {
        if (k < KW) f = W[m * ws + k];
        else if (k == KW) f = bias[m];
      }
      v[i] = f2bf_rne(f);
    }
    dst[kb] = v;
  }
}

template <int TC>
__device__ __forceinline__ void gemmN(const short* __restrict__ src, int rbase,
                                      const bf16x8 (&A)[TC][4],
                                      f32x4 (&acc)[TC]) {
#pragma unroll
  for (int t = 0; t < TC; ++t) acc[t] = {0.0f, 0.0f, 0.0f, 0.0f};
#pragma unroll
  for (int kb = 0; kb < 4; ++kb) {
    bf16x8 bv = *(const bf16x8*)(src + rbase + kb * 32);  // 16B aligned
#pragma unroll
    for (int t = 0; t < TC; ++t)
      acc[t] = __builtin_amdgcn_mfma_f32_16x16x32_bf16(A[t][kb], bv, acc[t], 0, 0, 0);
  }
}

// tanh + pack + b64 store per tile. Global tile g==6, quad==1, reg0 is h feat
// 100 -> force 1.0 (bias input feature for next layer).
template <int TC, int TO>
__device__ __forceinline__ void store_h(short* __restrict__ dst, int wrow,
                                        int quad, f32x4 (&acc)[TC]) {
#pragma unroll
  for (int t = 0; t < TC; ++t) {
    unsigned u0 = pack_bf2(fast_tanh(acc[t][0]), fast_tanh(acc[t][1]));
    unsigned u1 = pack_bf2(fast_tanh(acc[t][2]), fast_tanh(acc[t][3]));
    if constexpr (TO + 0 <= 6 && 6 < TO + TC) {
      if (TO + t == 6 && quad == 1) u0 = (u0 & 0xFFFF0000u) | 0x3F80u;
    }
    uintx2 v; v.x = u0; v.y = u1;
    *(uintx2*)(dst + wrow + (TO + t) * 16 + quad * 4) = v;
  }
}

// write x master as bf16; tile 6 quad 0 holds feats 96..99 = [x96, t, 1, 0].
template <int TC, int TO>
__device__ __forceinline__ void write_x(short* __restrict__ dst, int wrow,
                                        int quad, unsigned tbits,
                                        f32x4 (&xm)[TC]) {
#pragma unroll
  for (int t = 0; t < TC; ++t) {
    unsigned u0 = pack_bf2(xm[t][0], xm[t][1]);
    unsigned u1 = pack_bf2(xm[t][2], xm[t][3]);
    if constexpr (TO + 0 <= 6 && 6 < TO + TC) {
      if (TO + t == 6 && quad == 0) {
        u0 = (u0 & 0x0000FFFFu) | (tbits << 16);  // feat 97 = t
        u1 = 0x00003F80u;                         // feat 98 = 1.0, 99 = 0
      }
    }
    uintx2 v; v.x = u0; v.y = u1;
    *(uintx2*)(dst + wrow + (TO + t) * 16 + quad * 4) = v;
  }
}

template <int TC1, int TO1, int TC2, int TO2, int TC3, int TO3>
__device__ __forceinline__ void run_all(
    const float* __restrict__ series, const float* __restrict__ rand_error,
    const float* __restrict__ W1, const float* __restrict__ b1,
    const float* __restrict__ W2, const float* __restrict__ b2,
    const float* __restrict__ W3, const float* __restrict__ b3,
    float* __restrict__ out, short* bufP, short* bufQ, int rw, int col,
    int quad, int blk) {
  // ---- weights -> VGPR A-frags ----
  bf16x8 a1[TC1][4], a2[TC2][4], a3[TC3][4];
#pragma unroll
  for (int t = 0; t < TC1; ++t)
    load_afrag(W1, b1, QP2, NH, QP2, (TO1 + t) * 16 + col, quad, a1[t]);
#pragma unroll
  for (int t = 0; t < TC2; ++t)
    load_afrag(W2, b2, NH, NH, NH, (TO2 + t) * 16 + col, quad, a2[t]);
#pragma unroll
  for (int t = 0; t < TC3; ++t)
    load_afrag(W3, b3, NH, QP1, NH, (TO3 + t) * 16 + col, quad, a3[t]);

  const int grow = blk * ROWS + rw * 16 + col;  // global row
  const int gb = grow >> 4, gc = grow & 15;

  // ---- x0 (= noise) and x master, fp32 owner-lane regs ----
  f32x4 x0[TC3], xm[TC3];
#pragma unroll
  for (int t = 0; t < TC3; ++t)
#pragma unroll
    for (int r = 0; r < 4; ++r) {
      int q = (TO3 + t) * 16 + quad * 4 + r;
      float f = 0.0f;
      if (q < NQ) f = series[(gb * NQ + q) * NC + gc];
      else if (q == NQ) f = rand_error[gb * NC + gc];
      x0[t][r] = f;
      xm[t][r] = f;
    }

  const int wrow = (rw * 16 + col) * STR;
  const int rbase = wrow + quad * 8;

  write_x<TC3, TO3>(bufP, wrow, quad, 0u /*t=0*/, xm);
  __syncthreads();

  short* bx = bufP;
  short* bh = bufQ;

#pragma unroll 1
  for (int step = 0; step < NSTEPS_; ++step) {
    // L1: h1 = tanh([x,t,1] @ W1'^T)  read bx -> write bh
    {
      f32x4 acc[TC1];
      gemmN<TC1>(bx, rbase, a1, acc);
      store_h<TC1, TO1>(bh, wrow, quad, acc);
    }
    __syncthreads();
    // L2: h2 = tanh([h1,1] @ W2'^T)   read bh -> write bx (x only in regs now)
    {
      f32x4 acc[TC2];
      gemmN<TC2>(bh, rbase, a2, acc);
      store_h<TC2, TO2>(bx, wrow, quad, acc);
    }
    __syncthreads();
    // L3: pred = [h2,1] @ W3'^T ; x += (pred - x0)*dt ; write new x -> bh
    {
      f32x4 acc[TC3];
      gemmN<TC3>(bx, rbase, a3, acc);
#pragma unroll
      for (int t = 0; t < TC3; ++t)
#pragma unroll
        for (int r = 0; r < 4; ++r)
          xm[t][r] = fmaf(acc[t][r] - x0[t][r], 0.01f, xm[t][r]);
      float t1 = (float)(step + 1) * 0.01f;
      write_x<TC3, TO3>(bh, wrow, quad, bfhi(t1), xm);
    }
    __syncthreads();
    short* tp = bx; bx = bh; bh = tp;
  }

  // ---- final store: fp32 x -> out (B, 97, 16) ----
#pragma unroll
  for (int t = 0; t < TC3; ++t)
#pragma unroll
    for (int r = 0; r < 4; ++r) {
      int q = (TO3 + t) * 16 + quad * 4 + r;
      if (q < QP1) out[(gb * QP1 + q) * NC + gc] = xm[t][r];
    }
}

__global__ void __launch_bounds__(NTHR, 2)
arima_r4(const float* __restrict__ series, const float* __restrict__ rand_error,
         const float* __restrict__ W1, const float* __restrict__ b1,
         const float* __restrict__ W2, const float* __restrict__ b2,
         const float* __restrict__ W3, const float* __restrict__ b3,
         float* __restrict__ out) {
  __shared__ __align__(16) short bufP[ROWS * STR];
  __shared__ __align__(16) short bufQ[ROWS * STR];

  const int tid = threadIdx.x;
  const int w = tid >> 6, l = tid & 63;
  const int col = l & 15, quad = l >> 4;
  const int rw = w >> 1, nw = w & 1;

  // Zero both buffers: feats 112..127 are never written and poison bits can
  // be bf16-NaN -> NaN*0 = NaN through MFMA. Also feats beyond valid rely on
  // zero-weight columns, which needs finite operands.
  {
    int* zp = (int*)bufP;
    int* zq = (int*)bufQ;
    for (int i = tid; i < ROWS * STR / 2; i += NTHR) { zp[i] = 0; zq[i] = 0; }
  }
  __syncthreads();

  if (nw == 0) {
    // neuron tiles: L1 {0..3}, L2 {0..2}, L3 {0..3}  -> 11 tiles, 176 VGPR
    run_all<4, 0, 3, 0, 4, 0>(series, rand_error, W1, b1, W2, b2, W3, b3,
                              (float*)nullptr ? nullptr : nullptr, bufP, bufQ,
                              rw, col, quad, (int)blockIdx.x),
        (void)0;
  }
  // NOTE: out pointer must be passed properly; restructure below.
  if (nw == 0) {
    // (re-dispatch with correct out; the call above was removed)
  }
  // -- real dispatch --
  if (nw == 0) {
  } // placeholder removed in final code below
}

// The above block was a drafting artifact; the real kernel follows.

__global__ void __launch_bounds__(NTHR, 2)
arima_r4_real(const float* __restrict__ series,
              const float* __restrict__ rand_error,
              const float* __restrict__ W1, const float* __restrict__ b1,
              const float* __restrict__ W2, const float* __restrict__ b2,
              const float* __restrict__ W3, const float* __restrict__ b3,
              float* __restrict__ out) {
  __shared__ __align__(16) short bufP[ROWS * STR];
  __shared__ __align__(16) short bufQ[ROWS * STR];

  const int tid = threadIdx.x;
  const int w = tid >> 6, l = tid & 63;
  const int col = l & 15, quad = l >> 4;
  const int rw = w >> 1, nw = w & 1;

  {
    int* zp = (int*)bufP;
    int* zq = (int*)bufQ;
    for (int i = tid; i < ROWS * STR / 2; i += NTHR) { zp[i] = 0; zq[i] = 0; }
  }
  __syncthreads();

  if (nw == 0) {
    run_all<4, 0, 3, 0, 4, 0>(series, rand_error, W1, b1, W2, b2, W3, b3, out,
                              bufP, bufQ, rw, col, quad, (int)blockIdx.x);
  } else {
    run_all<3, 4, 4, 3, 3, 4>(series, rand_error, W1, b1, W2, b2, W3, b3, out,
                              bufP, bufQ, rw, col, quad, (int)blockIdx.x);
  }
}

extern "C" void kernel_launch(void* const* d_in, const int* in_sizes, int n_in,
                              void* d_out, int out_size, void* d_ws,
                              size_t ws_size, hipStream_t stream) {
  const float* series = (const float*)d_in[0];
  const float* rand_error = (const float*)d_in[1];
  const float* W1 = (const float*)d_in[2];
  const float* b1 = (const float*)d_in[3];
  const float* W2 = (const float*)d_in[4];
  const float* b2 = (const float*)d_in[5];
  const float* W3 = (const float*)d_in[6];
  const float* b3 = (const float*)d_in[7];
  float* out = (float*)d_out;

  dim3 grid((NB * NC) / ROWS);  // 512 WGs -> 2 WGs/CU (68 KB LDS, 2 waves/SIMD)
  dim3 block(NTHR);
  hipLaunchKernelGGL(arima_r4_real, grid, block, 0, stream, series, rand_error,
                     W1, b1, W2, b2, W3, b3, out);
}

// Round 5
// 288.963 us; speedup vs baseline: 1.1118x; 1.1118x over previous
//
#include <hip/hip_runtime.h>

// ARIMA flow sampling, R5: algebraic reformulation, 2 GEMMs/step.
//   z_s := W1'[x_s, t_s, 1]  (L1 preact, fp32 in MFMA accumulators)
//   h1 = tanh(z); h2 = tanh(W2'[h1,1])           (GEMM 1)
//   z += dtM @ h2 + v        dtM = dt*W1x@W3     (GEMM 2, acc_in = z)
//   x_100 = W3'[dt*sum_s h2_s, 1]                (one final GEMM; x_0 cancels
//                                                 exactly since 100*dt == 1)
// v = dt*(W1x b3 + b1 + w97) - dt*z_0 (per-row, regs). t folded into v.
// Prep kernel computes dtM (bf16 [128][128] pad) + s-vec into d_ws.
// Main: grid 1024 (WG = one batch, 16 rows=channels) x 256 thr (4 waves).
// Transposed MFMA: A = weights (VGPRs), B = activations (LDS [row][feat],
// bf16, STR=136, b128 reads / b64 writes). Uniform 8-tile neuron split
// (2 tiles/wave) - no divergent paths (R4 lesson: asymmetric dual-template
// inlining -> 128-VGPR cap + 73 MB/dispatch scratch spill traffic).

#define NB 1024
#define NQ 96
#define NC 16
#define NH 100
#define QP1 97
#define QP2 98
#define NTHR 256
#define STR 136
#define NSTEPS_ 100
#define MT_K 128  // dtM row stride (bf16)

typedef __attribute__((ext_vector_type(8))) short bf16x8;
typedef __attribute__((ext_vector_type(4))) float f32x4;
typedef __attribute__((ext_vector_type(2))) unsigned uintx2;

__device__ __forceinline__ short f2bf_rne(float f) {  // one-time paths only
  unsigned u = __builtin_bit_cast(unsigned, f);
  u = u + 0x7fffu + ((u >> 16) & 1u);
  return (short)(u >> 16);
}

// pack two half-up-rounded bf16 into one dword: lo=bf(a), hi=bf(b)
__device__ __forceinline__ unsigned pack_bf2(float a, float b) {
  unsigned ua = __builtin_bit_cast(unsigned, a) + 0x8000u;
  unsigned ub = __builtin_bit_cast(unsigned, b) + 0x8000u;
  return __builtin_amdgcn_perm(ub, ua, 0x07060302);
}

// Pade(5,4) tanh + clamp: max err ~7e-4, no transcendental except rcp.
__device__ __forceinline__ float fast_tanh(float x) {
  float u = x * x;
  float num = x * fmaf(u + 105.0f, u, 945.0f);
  float den = fmaf(fmaf(15.0f, u, 420.0f), u, 945.0f);
  float v = num * __builtin_amdgcn_rcpf(den);
  return fminf(fmaxf(v, -1.0f), 1.0f);
}

// ---------------- prep: dtM = dt * W1x @ W3 (bf16), s-vec ----------------
__global__ void __launch_bounds__(128) arima_prep(
    const float* __restrict__ W1, const float* __restrict__ b1,
    const float* __restrict__ W3, const float* __restrict__ b3,
    short* __restrict__ Mt, float* __restrict__ sv) {
  const int n = blockIdx.x;   // 0..127 (neuron; >=100 -> zero row)
  const int k = threadIdx.x;  // 0..127 (h2 feature; >=100 -> zero col)
  float acc = 0.0f;
  if (n < NH && k < NH) {
#pragma unroll 1
    for (int j = 0; j < QP1; ++j)
      acc = fmaf(W1[n * QP2 + j], W3[j * NH + k], acc);
  }
  Mt[n * MT_K + k] = f2bf_rne(0.01f * acc);
  if (k == 0) {
    float s = 0.0f;
    if (n < NH) {
      float d = 0.0f;
#pragma unroll 1
      for (int j = 0; j < QP1; ++j) d = fmaf(W1[n * QP2 + j], b3[j], d);
      s = 0.01f * (d + b1[n] + W1[n * QP2 + QP1]);  // dt*(W1x b3 + b1 + w97)
    }
    sv[n] = s;
  }
}

// ---------------- main ----------------
// Weight A-frag from fp32 W: lane holds W'[m][k], k<KW -> W, k==KW -> bias.
__device__ void load_afrag(const float* __restrict__ W,
                           const float* __restrict__ bias, int ws, int mvalid,
                           int KW, int m, int quad, bf16x8 dst[4]) {
#pragma unroll
  for (int kb = 0; kb < 4; ++kb) {
    bf16x8 v;
#pragma unroll
    for (int i = 0; i < 8; ++i) {
      int k = kb * 32 + quad * 8 + i;
      float f = 0.0f;
      if (m < mvalid) {
        if (k < KW) f = W[m * ws + k];
        else if (k == KW) f = bias[m];
      }
      v[i] = f2bf_rne(f);
    }
    dst[kb] = v;
  }
}

// acc += A * B(LDS). 2 tiles, K=128 (4 kb). acc carries in (z-update!).
__device__ __forceinline__ void gemm_acc(const short* __restrict__ src,
                                         int rbase, const bf16x8 (&A)[2][4],
                                         f32x4 (&acc)[2]) {
#pragma unroll
  for (int kb = 0; kb < 4; ++kb) {
    bf16x8 bv = *(const bf16x8*)(src + rbase + kb * 32);  // 16B aligned
    acc[0] = __builtin_amdgcn_mfma_f32_16x16x32_bf16(A[0][kb], bv, acc[0], 0, 0, 0);
    acc[1] = __builtin_amdgcn_mfma_f32_16x16x32_bf16(A[1][kb], bv, acc[1], 0, 0, 0);
  }
}

// pack + b64-store both tiles to [row][feat] layout.
__device__ __forceinline__ void write_tiles(short* __restrict__ dst, int wrow,
                                            int T0, int quad, const f32x4& v0,
                                            const f32x4& v1) {
  uintx2 a, b;
  a.x = pack_bf2(v0[0], v0[1]);
  a.y = pack_bf2(v0[2], v0[3]);
  b.x = pack_bf2(v1[0], v1[1]);
  b.y = pack_bf2(v1[2], v1[3]);
  *(uintx2*)(dst + wrow + T0 * 16 + quad * 4) = a;
  *(uintx2*)(dst + wrow + (T0 + 1) * 16 + quad * 4) = b;
}

__global__ void __launch_bounds__(NTHR, 3)
arima_r5(const float* __restrict__ series, const float* __restrict__ rand_error,
         const float* __restrict__ W1, const float* __restrict__ b1,
         const float* __restrict__ W2, const float* __restrict__ b2,
         const float* __restrict__ W3, const float* __restrict__ b3,
         const short* __restrict__ Mt, const float* __restrict__ sv,
         float* __restrict__ out) {
  __shared__ __align__(16) short buf1[16 * STR];  // h1 (feat 100 = 1.0)
  __shared__ __align__(16) short buf2[16 * STR];  // x0 / h2 / H2avg

  const int tid = threadIdx.x;
  const int w = tid >> 6, l = tid & 63;
  const int col = l & 15, quad = l >> 4;  // col = channel = data row
  const int b = blockIdx.x;               // WG = one batch
  const int T0 = 2 * w;                   // uniform: wave owns tiles 2w,2w+1
  const int wrow = col * STR;
  const int rbase = wrow + quad * 8;
  const bool fixw = (w == 3 && quad == 1);  // owns feat 100 (tile 6, reg 0)

  // ---- x0 -> buf2 : feats [x0(97), t0=0, 1, 0...] ----
  {
    f32x4 xv[2];
#pragma unroll
    for (int t = 0; t < 2; ++t)
#pragma unroll
      for (int r = 0; r < 4; ++r) {
        int q = (T0 + t) * 16 + quad * 4 + r;
        float f = 0.0f;
        if (q < NQ) f = series[(b * NQ + q) * NC + col];
        else if (q == NQ) f = rand_error[b * NC + col];
        else if (q == QP2) f = 1.0f;  // bias feature (q==97: t0 = 0)
        xv[t][r] = f;
      }
    write_tiles(buf2, wrow, T0, quad, xv[0], xv[1]);
  }
  __syncthreads();

  // ---- z0 = W1' x0row ; v = sv - dt*z0 ; h1_0 -> buf1 ----
  f32x4 z[2], v[2];
  {
    bf16x8 a1[2][4];  // transient: dead after this block
#pragma unroll
    for (int t = 0; t < 2; ++t)
      load_afrag(W1, b1, QP2, NH, QP2, (T0 + t) * 16 + col, quad, a1[t]);
    z[0] = {0.0f, 0.0f, 0.0f, 0.0f};
    z[1] = {0.0f, 0.0f, 0.0f, 0.0f};
    gemm_acc(buf2, rbase, a1, z);
#pragma unroll
    for (int t = 0; t < 2; ++t)
#pragma unroll
      for (int r = 0; r < 4; ++r)
        v[t][r] = sv[(T0 + t) * 16 + quad * 4 + r] - 0.01f * z[t][r];
  }
  {
    f32x4 h[2];
#pragma unroll
    for (int t = 0; t < 2; ++t)
#pragma unroll
      for (int r = 0; r < 4; ++r) h[t][r] = fast_tanh(z[t][r]);
    if (fixw) h[0][0] = 1.0f;  // h1 feat 100 = 1.0 (W2 bias input)
    write_tiles(buf1, wrow, T0, quad, h[0], h[1]);
  }
  __syncthreads();

  // ---- persistent frags: W2' + dtM ----
  bf16x8 a2[2][4], am[2][4];
#pragma unroll
  for (int t = 0; t < 2; ++t) {
    load_afrag(W2, b2, NH, NH, NH, (T0 + t) * 16 + col, quad, a2[t]);
#pragma unroll
    for (int kb = 0; kb < 4; ++kb)
      am[t][kb] = *(const bf16x8*)(Mt + ((T0 + t) * 16 + col) * MT_K +
                                   kb * 32 + quad * 8);
  }
  f32x4 h2s[2] = {{0.0f, 0.0f, 0.0f, 0.0f}, {0.0f, 0.0f, 0.0f, 0.0f}};

#pragma unroll 1
  for (int step = 0; step < NSTEPS_; ++step) {
    // GEMM 1: h2 = tanh(W2'[h1,1]); accumulate H2sum; write h2 -> buf2
    f32x4 acc[2], h[2];
    acc[0] = {0.0f, 0.0f, 0.0f, 0.0f};
    acc[1] = {0.0f, 0.0f, 0.0f, 0.0f};
    gemm_acc(buf1, rbase, a2, acc);
#pragma unroll
    for (int t = 0; t < 2; ++t)
#pragma unroll
      for (int r = 0; r < 4; ++r) {
        h[t][r] = fast_tanh(acc[t][r]);
        h2s[t][r] += h[t][r];
      }
    write_tiles(buf2, wrow, T0, quad, h[0], h[1]);
    __syncthreads();
    // GEMM 2: z += dtM h2 (acc_in = z!), z += v ; h1' = tanh(z) -> buf1
    gemm_acc(buf2, rbase, am, z);
#pragma unroll
    for (int t = 0; t < 2; ++t)
#pragma unroll
      for (int r = 0; r < 4; ++r) {
        z[t][r] += v[t][r];
        h[t][r] = fast_tanh(z[t][r]);
      }
    if (fixw) h[0][0] = 1.0f;
    write_tiles(buf1, wrow, T0, quad, h[0], h[1]);
    __syncthreads();
  }

  // ---- out = W3'[dt*H2sum, 1] ----
  {
    f32x4 ha[2];
#pragma unroll
    for (int t = 0; t < 2; ++t)
#pragma unroll
      for (int r = 0; r < 4; ++r) ha[t][r] = 0.01f * h2s[t][r];
    if (fixw) ha[0][0] = 1.0f;  // bias feature for b3
    write_tiles(buf2, wrow, T0, quad, ha[0], ha[1]);
  }
  __syncthreads();
  {
    bf16x8 a3[2][4];
#pragma unroll
    for (int t = 0; t < 2; ++t)
      load_afrag(W3, b3, NH, QP1, NH, (T0 + t) * 16 + col, quad, a3[t]);
    f32x4 o[2];
    o[0] = {0.0f, 0.0f, 0.0f, 0.0f};
    o[1] = {0.0f, 0.0f, 0.0f, 0.0f};
    gemm_acc(buf2, rbase, a3, o);
#pragma unroll
    for (int t = 0; t < 2; ++t)
#pragma unroll
      for (int r = 0; r < 4; ++r) {
        int q = (T0 + t) * 16 + quad * 4 + r;
        if (q < QP1) out[(b * QP1 + q) * NC + col] = o[t][r];
      }
  }
}

extern "C" void kernel_launch(void* const* d_in, const int* in_sizes, int n_in,
                              void* d_out, int out_size, void* d_ws,
                              size_t ws_size, hipStream_t stream) {
  const float* series = (const float*)d_in[0];
  const float* rand_error = (const float*)d_in[1];
  const float* W1 = (const float*)d_in[2];
  const float* b1 = (const float*)d_in[3];
  const float* W2 = (const float*)d_in[4];
  const float* b2 = (const float*)d_in[5];
  const float* W3 = (const float*)d_in[6];
  const float* b3 = (const float*)d_in[7];
  float* out = (float*)d_out;

  short* Mt = (short*)d_ws;                        // 128*128 bf16 = 32768 B
  float* sv = (float*)((char*)d_ws + 128 * 128 * 2);  // 128 f32

  hipLaunchKernelGGL(arima_prep, dim3(128), dim3(128), 0, stream, W1, b1, W3,
                     b3, Mt, sv);
  hipLaunchKernelGGL(arima_r5, dim3(NB), dim3(NTHR), 0, stream, series,
                     rand_error, W1, b1, W2, b2, W3, b3, Mt, sv, out);
}

// Round 9
// 267.724 us; speedup vs baseline: 1.2000x; 1.0793x over previous
//
#include <hip/hip_runtime.h>

// ARIMA flow sampling, R9 = R5's VERIFIED bf16 main kernel (passed, absmax
// 0.0078) + parallel prep + __launch_bounds__(256,4).
// R7/R8 f16 port failed with BIT-IDENTICAL absmax (1.863281) -> error source
// invariant to tanh details, shared by both, absent in bf16 R5. Prime suspect
// after line-audit: unverified f16 MFMA A/B fragment layout (all passing
// kernels used bf16 MFMA). Reverting to the verified dtype; banking the two
// safe wins instead (prep was ~65us serial; occupancy 3->4 blocks/CU).
//
// Algebra:
//   z_s := W1'[x_s, t_s, 1]  (L1 preact, fp32 in MFMA accumulators)
//   h1 = tanh(z); h2 = tanh(W2'[h1,1])           (GEMM 1)
//   z += dtM @ h2 + v        dtM = dt*W1x@W3     (GEMM 2, acc_in = z)
//   x_100 = W3'[dt*sum_s h2_s, 1]                (x_0 cancels: 100*dt == 1)
// v = dt*(W1x b3 + b1 + w97) - dt*z_0 per-row in regs; t folded into v.

#define NB 1024
#define NQ 96
#define NC 16
#define NH 100
#define QP1 97
#define QP2 98
#define NTHR 256
#define STR 136
#define NSTEPS_ 100
#define MT_K 128  // dtM row stride (bf16)

typedef __attribute__((ext_vector_type(8))) short bf16x8;
typedef __attribute__((ext_vector_type(4))) float f32x4;
typedef __attribute__((ext_vector_type(2))) unsigned uintx2;

__device__ __forceinline__ short f2bf_rne(float f) {  // one-time paths only
  unsigned u = __builtin_bit_cast(unsigned, f);
  u = u + 0x7fffu + ((u >> 16) & 1u);
  return (short)(u >> 16);
}

// pack two half-up-rounded bf16 into one dword: lo=bf(a), hi=bf(b)
__device__ __forceinline__ unsigned pack_bf2(float a, float b) {
  unsigned ua = __builtin_bit_cast(unsigned, a) + 0x8000u;
  unsigned ub = __builtin_bit_cast(unsigned, b) + 0x8000u;
  return __builtin_amdgcn_perm(ub, ua, 0x07060302);
}

// Pade(5,4) tanh + clamp: max err ~7e-4, f32, one rcp.
__device__ __forceinline__ float fast_tanh(float x) {
  float u = x * x;
  float num = x * fmaf(u + 105.0f, u, 945.0f);
  float den = fmaf(fmaf(15.0f, u, 420.0f), u, 945.0f);
  float v = num * __builtin_amdgcn_rcpf(den);
  return fminf(fmaxf(v, -1.0f), 1.0f);
}

// ---------------- prep: dtM = dt * W1x @ W3 (bf16) + s-vec ----------------
// grid 128 (= n), block 512 (k = tid&127, jslice = tid>>7); LDS reduce.
__global__ void __launch_bounds__(512) arima_prep(
    const float* __restrict__ W1, const float* __restrict__ b1,
    const float* __restrict__ W3, const float* __restrict__ b3,
    short* __restrict__ Mt, float* __restrict__ sv) {
  __shared__ float part[4][128];
  __shared__ float pb[128];
  const int n = blockIdx.x;
  const int tid = threadIdx.x;
  const int k = tid & 127, js = tid >> 7;
  float s = 0.0f;
  if (n < NH && k < NH) {
    int j0 = js * 25, j1 = (js == 3) ? QP1 : j0 + 25;
    for (int j = j0; j < j1; ++j)
      s = fmaf(W1[n * QP2 + j], W3[j * NH + k], s);
  }
  part[js][k] = s;
  if (tid < 128)
    pb[tid] = (tid < QP1 && n < NH) ? W1[n * QP2 + tid] * b3[tid] : 0.0f;
  __syncthreads();
  if (js == 0) {
    float tot = part[0][k] + part[1][k] + part[2][k] + part[3][k];
    Mt[n * MT_K + k] = f2bf_rne(0.01f * tot);
  }
  if (tid == 0) {
    float d = 0.0f;
    for (int j = 0; j < 128; ++j) d += pb[j];
    sv[n] = (n < NH) ? 0.01f * (d + b1[n] + W1[n * QP2 + QP1]) : 0.0f;
  }
}

// ---------------- main (identical to verified R5) ----------------
// Weight A-frag from fp32 W: lane holds W'[m][k], k<KW -> W, k==KW -> bias.
__device__ void load_afrag(const float* __restrict__ W,
                           const float* __restrict__ bias, int ws, int mvalid,
                           int KW, int m, int quad, bf16x8 dst[4]) {
#pragma unroll
  for (int kb = 0; kb < 4; ++kb) {
    bf16x8 v;
#pragma unroll
    for (int i = 0; i < 8; ++i) {
      int k = kb * 32 + quad * 8 + i;
      float f = 0.0f;
      if (m < mvalid) {
        if (k < KW) f = W[m * ws + k];
        else if (k == KW) f = bias[m];
      }
      v[i] = f2bf_rne(f);
    }
    dst[kb] = v;
  }
}

// acc += A * B(LDS). 2 tiles, K=128 (4 kb). acc carries in (z-update!).
__device__ __forceinline__ void gemm_acc(const short* __restrict__ src,
                                         int rbase, const bf16x8 (&A)[2][4],
                                         f32x4 (&acc)[2]) {
#pragma unroll
  for (int kb = 0; kb < 4; ++kb) {
    bf16x8 bv = *(const bf16x8*)(src + rbase + kb * 32);  // 16B aligned
    acc[0] = __builtin_amdgcn_mfma_f32_16x16x32_bf16(A[0][kb], bv, acc[0], 0, 0, 0);
    acc[1] = __builtin_amdgcn_mfma_f32_16x16x32_bf16(A[1][kb], bv, acc[1], 0, 0, 0);
  }
}

// pack + b64-store both tiles to [row][feat] layout.
__device__ __forceinline__ void write_tiles(short* __restrict__ dst, int wrow,
                                            int T0, int quad, const f32x4& v0,
                                            const f32x4& v1) {
  uintx2 a, b;
  a.x = pack_bf2(v0[0], v0[1]);
  a.y = pack_bf2(v0[2], v0[3]);
  b.x = pack_bf2(v1[0], v1[1]);
  b.y = pack_bf2(v1[2], v1[3]);
  *(uintx2*)(dst + wrow + T0 * 16 + quad * 4) = a;
  *(uintx2*)(dst + wrow + (T0 + 1) * 16 + quad * 4) = b;
}

__global__ void __launch_bounds__(NTHR, 4)
arima_r9(const float* __restrict__ series, const float* __restrict__ rand_error,
         const float* __restrict__ W1, const float* __restrict__ b1,
         const float* __restrict__ W2, const float* __restrict__ b2,
         const float* __restrict__ W3, const float* __restrict__ b3,
         const short* __restrict__ Mt, const float* __restrict__ sv,
         float* __restrict__ out) {
  __shared__ __align__(16) short buf1[16 * STR];  // h1 (feat 100 = 1.0)
  __shared__ __align__(16) short buf2[16 * STR];  // x0 / h2 / H2avg

  const int tid = threadIdx.x;
  const int w = tid >> 6, l = tid & 63;
  const int col = l & 15, quad = l >> 4;  // col = channel = data row
  const int b = blockIdx.x;               // WG = one batch
  const int T0 = 2 * w;                   // uniform: wave owns tiles 2w,2w+1
  const int wrow = col * STR;
  const int rbase = wrow + quad * 8;
  const bool fixw = (w == 3 && quad == 1);  // owns feat 100 (tile 6, reg 0)

  // ---- x0 -> buf2 : feats [x0(97), t0=0, 1, 0...] ----
  {
    f32x4 xv[2];
#pragma unroll
    for (int t = 0; t < 2; ++t)
#pragma unroll
      for (int r = 0; r < 4; ++r) {
        int q = (T0 + t) * 16 + quad * 4 + r;
        float f = 0.0f;
        if (q < NQ) f = series[(b * NQ + q) * NC + col];
        else if (q == NQ) f = rand_error[b * NC + col];
        else if (q == QP2) f = 1.0f;  // bias feature (q==97: t0 = 0)
        xv[t][r] = f;
      }
    write_tiles(buf2, wrow, T0, quad, xv[0], xv[1]);
  }
  __syncthreads();

  // ---- z0 = W1'[x0,0,1] ; v = sv - dt*z0 ; h1_0 -> buf1 ----
  f32x4 z[2], v[2];
  {
    bf16x8 a1[2][4];  // transient
#pragma unroll
    for (int t = 0; t < 2; ++t)
      load_afrag(W1, b1, QP2, NH, QP2, (T0 + t) * 16 + col, quad, a1[t]);
    z[0] = {0.0f, 0.0f, 0.0f, 0.0f};
    z[1] = {0.0f, 0.0f, 0.0f, 0.0f};
    gemm_acc(buf2, rbase, a1, z);
#pragma unroll
    for (int t = 0; t < 2; ++t)
#pragma unroll
      for (int r = 0; r < 4; ++r)
        v[t][r] = sv[(T0 + t) * 16 + quad * 4 + r] - 0.01f * z[t][r];
  }
  {
    f32x4 h[2];
#pragma unroll
    for (int t = 0; t < 2; ++t)
#pragma unroll
      for (int r = 0; r < 4; ++r) h[t][r] = fast_tanh(z[t][r]);
    if (fixw) h[0][0] = 1.0f;  // h1 feat 100 = 1.0 (W2 bias input)
    write_tiles(buf1, wrow, T0, quad, h[0], h[1]);
  }
  __syncthreads();

  // ---- persistent frags: W2' + dtM ----
  bf16x8 a2[2][4], am[2][4];
#pragma unroll
  for (int t = 0; t < 2; ++t) {
    load_afrag(W2, b2, NH, NH, NH, (T0 + t) * 16 + col, quad, a2[t]);
#pragma unroll
    for (int kb = 0; kb < 4; ++kb)
      am[t][kb] = *(const bf16x8*)(Mt + ((T0 + t) * 16 + col) * MT_K +
                                   kb * 32 + quad * 8);
  }
  f32x4 h2s[2] = {{0.0f, 0.0f, 0.0f, 0.0f}, {0.0f, 0.0f, 0.0f, 0.0f}};

#pragma unroll 1
  for (int step = 0; step < NSTEPS_; ++step) {
    // GEMM 1: h2 = tanh(W2'[h1,1]); accumulate H2sum; write h2 -> buf2
    f32x4 acc[2], h[2];
    acc[0] = {0.0f, 0.0f, 0.0f, 0.0f};
    acc[1] = {0.0f, 0.0f, 0.0f, 0.0f};
    gemm_acc(buf1, rbase, a2, acc);
#pragma unroll
    for (int t = 0; t < 2; ++t)
#pragma unroll
      for (int r = 0; r < 4; ++r) {
        h[t][r] = fast_tanh(acc[t][r]);
        h2s[t][r] += h[t][r];
      }
    write_tiles(buf2, wrow, T0, quad, h[0], h[1]);
    __syncthreads();
    // GEMM 2: z += dtM h2 (acc_in = z!), z += v ; h1' = tanh(z) -> buf1
    gemm_acc(buf2, rbase, am, z);
#pragma unroll
    for (int t = 0; t < 2; ++t)
#pragma unroll
      for (int r = 0; r < 4; ++r) {
        z[t][r] += v[t][r];
        h[t][r] = fast_tanh(z[t][r]);
      }
    if (fixw) h[0][0] = 1.0f;
    write_tiles(buf1, wrow, T0, quad, h[0], h[1]);
    __syncthreads();
  }

  // ---- out = W3'[dt*H2sum, 1] ----
  {
    f32x4 ha[2];
#pragma unroll
    for (int t = 0; t < 2; ++t)
#pragma unroll
      for (int r = 0; r < 4; ++r) ha[t][r] = 0.01f * h2s[t][r];
    if (fixw) ha[0][0] = 1.0f;  // bias feature for b3
    write_tiles(buf2, wrow, T0, quad, ha[0], ha[1]);
  }
  __syncthreads();
  {
    bf16x8 a3[2][4];
#pragma unroll
    for (int t = 0; t < 2; ++t)
      load_afrag(W3, b3, NH, QP1, NH, (T0 + t) * 16 + col, quad, a3[t]);
    f32x4 o[2];
    o[0] = {0.0f, 0.0f, 0.0f, 0.0f};
    o[1] = {0.0f, 0.0f, 0.0f, 0.0f};
    gemm_acc(buf2, rbase, a3, o);
#pragma unroll
    for (int t = 0; t < 2; ++t)
#pragma unroll
      for (int r = 0; r < 4; ++r) {
        int q = (T0 + t) * 16 + quad * 4 + r;
        if (q < QP1) out[(b * QP1 + q) * NC + col] = o[t][r];
      }
  }
}

extern "C" void kernel_launch(void* const* d_in, const int* in_sizes, int n_in,
                              void* d_out, int out_size, void* d_ws,
                              size_t ws_size, hipStream_t stream) {
  const float* series = (const float*)d_in[0];
  const float* rand_error = (const float*)d_in[1];
  const float* W1 = (const float*)d_in[2];
  const float* b1 = (const float*)d_in[3];
  const float* W2 = (const float*)d_in[4];
  const float* b2 = (const float*)d_in[5];
  const float* W3 = (const float*)d_in[6];
  const float* b3 = (const float*)d_in[7];
  float* out = (float*)d_out;

  short* Mt = (short*)d_ws;                           // 128*128*2 = 32768 B
  float* sv = (float*)((char*)d_ws + MT_K * MT_K * 2);  // 128 f32

  hipLaunchKernelGGL(arima_prep, dim3(128), dim3(512), 0, stream, W1, b1, W3,
                     b3, Mt, sv);
  hipLaunchKernelGGL(arima_r9, dim3(NB), dim3(NTHR), 0, stream, series,
                     rand_error, W1, b1, W2, b2, W3, b3, Mt, sv, out);
}

// Round 10
// 263.380 us; speedup vs baseline: 1.2197x; 1.0165x over previous
//
#include <hip/hip_runtime.h>

// ARIMA flow sampling, R10 = R9 (verified bf16 MFMA, absmax 0.0078) with the
// VALU epilogue vectorized to f32x4 ops so the backend can select packed-fp32
// VOP3P (v_pk_fma_f32 etc., full-rate on gfx90a+). Per-element math is
// IDENTICAL to R9 -> absmax must stay exactly 0.0078125 (rewrite tripwire).
// R9 counters: VALUBusy 70 + MfmaUtil 21 = issue-bound; tanh poly dominates.
//
// Algebra:
//   z_s := W1'[x_s, t_s, 1]  (L1 preact, fp32 in MFMA accumulators)
//   h1 = tanh(z); h2 = tanh(W2'[h1,1])           (GEMM 1)
//   z += dtM @ h2 + v        dtM = dt*W1x@W3     (GEMM 2, acc_in = z)
//   x_100 = W3'[dt*sum_s h2_s, 1]                (x_0 cancels: 100*dt == 1)
// v = dt*(W1x b3 + b1 + w97) - dt*z_0 per-row in regs; t folded into v.

#define NB 1024
#define NQ 96
#define NC 16
#define NH 100
#define QP1 97
#define QP2 98
#define NTHR 256
#define STR 136
#define NSTEPS_ 100
#define MT_K 128  // dtM row stride (bf16)

typedef __attribute__((ext_vector_type(8))) short bf16x8;
typedef __attribute__((ext_vector_type(4))) float f32x4;
typedef __attribute__((ext_vector_type(2))) unsigned uintx2;

__device__ __forceinline__ f32x4 splat4(float f) {
  f32x4 v = f;
  return v;
}

__device__ __forceinline__ short f2bf_rne(float f) {  // one-time paths only
  unsigned u = __builtin_bit_cast(unsigned, f);
  u = u + 0x7fffu + ((u >> 16) & 1u);
  return (short)(u >> 16);
}

// pack two half-up-rounded bf16 into one dword: lo=bf(a), hi=bf(b)
__device__ __forceinline__ unsigned pack_bf2(float a, float b) {
  unsigned ua = __builtin_bit_cast(unsigned, a) + 0x8000u;
  unsigned ub = __builtin_bit_cast(unsigned, b) + 0x8000u;
  return __builtin_amdgcn_perm(ub, ua, 0x07060302);
}

// Pade(5,4) tanh on f32x4 (identical per-element math to R9's scalar path;
// vector form lets the backend form v_pk_fma_f32/v_pk_mul_f32 pairs).
__device__ __forceinline__ f32x4 tanh4(f32x4 x) {
  f32x4 u = x * x;
  f32x4 num = x * __builtin_elementwise_fma(u + splat4(105.0f), u, splat4(945.0f));
  f32x4 den = __builtin_elementwise_fma(
      __builtin_elementwise_fma(splat4(15.0f), u, splat4(420.0f)), u,
      splat4(945.0f));
  f32x4 r;
  r[0] = __builtin_amdgcn_rcpf(den[0]);
  r[1] = __builtin_amdgcn_rcpf(den[1]);
  r[2] = __builtin_amdgcn_rcpf(den[2]);
  r[3] = __builtin_amdgcn_rcpf(den[3]);
  f32x4 v = num * r;
  return __builtin_elementwise_min(
      __builtin_elementwise_max(v, splat4(-1.0f)), splat4(1.0f));
}

// ---------------- prep: dtM = dt * W1x @ W3 (bf16) + s-vec ----------------
// grid 128 (= n), block 512 (k = tid&127, jslice = tid>>7); LDS reduce.
__global__ void __launch_bounds__(512) arima_prep(
    const float* __restrict__ W1, const float* __restrict__ b1,
    const float* __restrict__ W3, const float* __restrict__ b3,
    short* __restrict__ Mt, float* __restrict__ sv) {
  __shared__ float part[4][128];
  __shared__ float pb[128];
  const int n = blockIdx.x;
  const int tid = threadIdx.x;
  const int k = tid & 127, js = tid >> 7;
  float s = 0.0f;
  if (n < NH && k < NH) {
    int j0 = js * 25, j1 = (js == 3) ? QP1 : j0 + 25;
    for (int j = j0; j < j1; ++j)
      s = fmaf(W1[n * QP2 + j], W3[j * NH + k], s);
  }
  part[js][k] = s;
  if (tid < 128)
    pb[tid] = (tid < QP1 && n < NH) ? W1[n * QP2 + tid] * b3[tid] : 0.0f;
  __syncthreads();
  if (js == 0) {
    float tot = part[0][k] + part[1][k] + part[2][k] + part[3][k];
    Mt[n * MT_K + k] = f2bf_rne(0.01f * tot);
  }
  if (tid == 0) {
    float d = 0.0f;
    for (int j = 0; j < 128; ++j) d += pb[j];
    sv[n] = (n < NH) ? 0.01f * (d + b1[n] + W1[n * QP2 + QP1]) : 0.0f;
  }
}

// ---------------- main ----------------
// Weight A-frag from fp32 W: lane holds W'[m][k], k<KW -> W, k==KW -> bias.
__device__ void load_afrag(const float* __restrict__ W,
                           const float* __restrict__ bias, int ws, int mvalid,
                           int KW, int m, int quad, bf16x8 dst[4]) {
#pragma unroll
  for (int kb = 0; kb < 4; ++kb) {
    bf16x8 v;
#pragma unroll
    for (int i = 0; i < 8; ++i) {
      int k = kb * 32 + quad * 8 + i;
      float f = 0.0f;
      if (m < mvalid) {
        if (k < KW) f = W[m * ws + k];
        else if (k == KW) f = bias[m];
      }
      v[i] = f2bf_rne(f);
    }
    dst[kb] = v;
  }
}

// acc += A * B(LDS). 2 tiles, K=128 (4 kb). acc carries in (z-update!).
__device__ __forceinline__ void gemm_acc(const short* __restrict__ src,
                                         int rbase, const bf16x8 (&A)[2][4],
                                         f32x4 (&acc)[2]) {
#pragma unroll
  for (int kb = 0; kb < 4; ++kb) {
    bf16x8 bv = *(const bf16x8*)(src + rbase + kb * 32);  // 16B aligned
    acc[0] = __builtin_amdgcn_mfma_f32_16x16x32_bf16(A[0][kb], bv, acc[0], 0, 0, 0);
    acc[1] = __builtin_amdgcn_mfma_f32_16x16x32_bf16(A[1][kb], bv, acc[1], 0, 0, 0);
  }
}

// pack + b64-store both tiles to [row][feat] layout.
__device__ __forceinline__ void write_tiles(short* __restrict__ dst, int wrow,
                                            int T0, int quad, const f32x4& v0,
                                            const f32x4& v1) {
  uintx2 a, b;
  a.x = pack_bf2(v0[0], v0[1]);
  a.y = pack_bf2(v0[2], v0[3]);
  b.x = pack_bf2(v1[0], v1[1]);
  b.y = pack_bf2(v1[2], v1[3]);
  *(uintx2*)(dst + wrow + T0 * 16 + quad * 4) = a;
  *(uintx2*)(dst + wrow + (T0 + 1) * 16 + quad * 4) = b;
}

__global__ void __launch_bounds__(NTHR, 4)
arima_r10(const float* __restrict__ series,
          const float* __restrict__ rand_error, const float* __restrict__ W1,
          const float* __restrict__ b1, const float* __restrict__ W2,
          const float* __restrict__ b2, const float* __restrict__ W3,
          const float* __restrict__ b3, const short* __restrict__ Mt,
          const float* __restrict__ sv, float* __restrict__ out) {
  __shared__ __align__(16) short buf1[16 * STR];  // h1 (feat 100 = 1.0)
  __shared__ __align__(16) short buf2[16 * STR];  // x0 / h2 / H2avg

  const int tid = threadIdx.x;
  const int w = tid >> 6, l = tid & 63;
  const int col = l & 15, quad = l >> 4;  // col = channel = data row
  const int b = blockIdx.x;               // WG = one batch
  const int T0 = 2 * w;                   // uniform: wave owns tiles 2w,2w+1
  const int wrow = col * STR;
  const int rbase = wrow + quad * 8;
  const bool fixw = (w == 3 && quad == 1);  // owns feat 100 (tile 6, reg 0)

  // ---- x0 -> buf2 : feats [x0(97), t0=0, 1, 0...] ----
  {
    f32x4 xv[2];
#pragma unroll
    for (int t = 0; t < 2; ++t)
#pragma unroll
      for (int r = 0; r < 4; ++r) {
        int q = (T0 + t) * 16 + quad * 4 + r;
        float f = 0.0f;
        if (q < NQ) f = series[(b * NQ + q) * NC + col];
        else if (q == NQ) f = rand_error[b * NC + col];
        else if (q == QP2) f = 1.0f;  // bias feature (q==97: t0 = 0)
        xv[t][r] = f;
      }
    write_tiles(buf2, wrow, T0, quad, xv[0], xv[1]);
  }
  __syncthreads();

  // ---- z0 = W1'[x0,0,1] ; v = sv - dt*z0 ; h1_0 -> buf1 ----
  f32x4 z[2], v[2];
  {
    bf16x8 a1[2][4];  // transient
#pragma unroll
    for (int t = 0; t < 2; ++t)
      load_afrag(W1, b1, QP2, NH, QP2, (T0 + t) * 16 + col, quad, a1[t]);
    z[0] = splat4(0.0f);
    z[1] = splat4(0.0f);
    gemm_acc(buf2, rbase, a1, z);
#pragma unroll
    for (int t = 0; t < 2; ++t) {
      f32x4 s;
#pragma unroll
      for (int r = 0; r < 4; ++r) s[r] = sv[(T0 + t) * 16 + quad * 4 + r];
      v[t] = s - splat4(0.01f) * z[t];
    }
  }
  {
    f32x4 h0 = tanh4(z[0]), h1 = tanh4(z[1]);
    if (fixw) h0[0] = 1.0f;  // h1 feat 100 = 1.0 (W2 bias input)
    write_tiles(buf1, wrow, T0, quad, h0, h1);
  }
  __syncthreads();

  // ---- persistent frags: W2' + dtM ----
  bf16x8 a2[2][4], am[2][4];
#pragma unroll
  for (int t = 0; t < 2; ++t) {
    load_afrag(W2, b2, NH, NH, NH, (T0 + t) * 16 + col, quad, a2[t]);
#pragma unroll
    for (int kb = 0; kb < 4; ++kb)
      am[t][kb] = *(const bf16x8*)(Mt + ((T0 + t) * 16 + col) * MT_K +
                                   kb * 32 + quad * 8);
  }
  f32x4 h2s[2] = {splat4(0.0f), splat4(0.0f)};

#pragma unroll 1
  for (int step = 0; step < NSTEPS_; ++step) {
    // GEMM 1: h2 = tanh(W2'[h1,1]); store FIRST (shorten other waves'
    // barrier wait), then accumulate H2sum.
    f32x4 acc[2];
    acc[0] = splat4(0.0f);
    acc[1] = splat4(0.0f);
    gemm_acc(buf1, rbase, a2, acc);
    {
      f32x4 h0 = tanh4(acc[0]), h1 = tanh4(acc[1]);
      write_tiles(buf2, wrow, T0, quad, h0, h1);
      h2s[0] = h2s[0] + h0;
      h2s[1] = h2s[1] + h1;
    }
    __syncthreads();
    // GEMM 2: z += dtM h2 (acc_in = z!), z += v ; h1' = tanh(z) -> buf1
    gemm_acc(buf2, rbase, am, z);
    {
      z[0] = z[0] + v[0];
      z[1] = z[1] + v[1];
      f32x4 h0 = tanh4(z[0]), h1 = tanh4(z[1]);
      if (fixw) h0[0] = 1.0f;
      write_tiles(buf1, wrow, T0, quad, h0, h1);
    }
    __syncthreads();
  }

  // ---- out = W3'[dt*H2sum, 1] ----
  {
    f32x4 ha0 = splat4(0.01f) * h2s[0];
    f32x4 ha1 = splat4(0.01f) * h2s[1];
    if (fixw) ha0[0] = 1.0f;  // bias feature for b3
    write_tiles(buf2, wrow, T0, quad, ha0, ha1);
  }
  __syncthreads();
  {
    bf16x8 a3[2][4];
#pragma unroll
    for (int t = 0; t < 2; ++t)
      load_afrag(W3, b3, NH, QP1, NH, (T0 + t) * 16 + col, quad, a3[t]);
    f32x4 o[2];
    o[0] = splat4(0.0f);
    o[1] = splat4(0.0f);
    gemm_acc(buf2, rbase, a3, o);
#pragma unroll
    for (int t = 0; t < 2; ++t)
#pragma unroll
      for (int r = 0; r < 4; ++r) {
        int q = (T0 + t) * 16 + quad * 4 + r;
        if (q < QP1) out[(b * QP1 + q) * NC + col] = o[t][r];
      }
  }
}

extern "C" void kernel_launch(void* const* d_in, const int* in_sizes, int n_in,
                              void* d_out, int out_size, void* d_ws,
                              size_t ws_size, hipStream_t stream) {
  const float* series = (const float*)d_in[0];
  const float* rand_error = (const float*)d_in[1];
  const float* W1 = (const float*)d_in[2];
  const float* b1 = (const float*)d_in[3];
  const float* W2 = (const float*)d_in[4];
  const float* b2 = (const float*)d_in[5];
  const float* W3 = (const float*)d_in[6];
  const float* b3 = (const float*)d_in[7];
  float* out = (float*)d_out;

  short* Mt = (short*)d_ws;                             // 128*128*2 = 32768 B
  float* sv = (float*)((char*)d_ws + MT_K * MT_K * 2);  // 128 f32

  hipLaunchKernelGGL(arima_prep, dim3(128), dim3(512), 0, stream, W1, b1, W3,
                     b3, Mt, sv);
  hipLaunchKernelGGL(arima_r10, dim3(NB), dim3(NTHR), 0, stream, series,
                     rand_error, W1, b1, W2, b2, W3, b3, Mt, sv, out);
}